// Round 1
// baseline (3766.776 us; speedup 1.0000x reference)
//
#include <hip/hip_runtime.h>

#define E_EDGES 640000
#define NN 10000
#define HID 32
#define EDIM 128

typedef _Float16 f16;
typedef _Float16 f16x8 __attribute__((ext_vector_type(8)));
typedef float f32x4 __attribute__((ext_vector_type(4)));

// ---------------- prep: zero agg, build f16 fragment-ordered weights ----------------
// Wf layout:  [c2:33][h:2][lane:64][r:8]  value = W2ext[k=c2][i*32+j], i=(l&15)+16h, j=(l>>4)*8+r
//             (c2==32 row is b2, paired with ones-row of h1)
// W1f layout: [c:4][h:2][lane:64][r:8]   value = w1[d][k], d=c*32+(l>>4)*8+r, k=(l&15)+16h
__global__ __launch_bounds__(256) void prep_kernel(
    const float* __restrict__ w1, const float* __restrict__ w2,
    const float* __restrict__ b2, float* __restrict__ agg,
    f16* __restrict__ Wf, f16* __restrict__ W1f)
{
  int tid = blockIdx.x * 256 + threadIdx.x;
  if (tid < NN * HID) agg[tid] = 0.f;
  if (tid < 33 * 1024) {
    int r = tid & 7, l = (tid >> 3) & 63, h = (tid >> 9) & 1, c2 = tid >> 10;
    int i = (l & 15) + 16 * h, j = (l >> 4) * 8 + r;
    float v = (c2 < 32) ? w2[c2 * 1024 + i * 32 + j] : b2[i * 32 + j];
    Wf[tid] = (f16)v;
  }
  if (tid < 4 * 1024) {
    int r = tid & 7, l = (tid >> 3) & 63, h = (tid >> 9) & 1, c = tid >> 10;
    int d = c * 32 + (l >> 4) * 8 + r, k = (l & 15) + 16 * h;
    W1f[tid] = (f16)w1[d * 32 + k];
  }
}

// ---------------- edges: h1 = relu(ea@W1+b1); messages = Z@W; atomic scatter ----------------
// One wave per 16-edge tile, 4 waves / block.
__global__ __launch_bounds__(256) void edges_kernel(
    const float* __restrict__ x, const int* __restrict__ ei,
    const float* __restrict__ ea, const float* __restrict__ b1,
    const f16* __restrict__ Wf, const f16* __restrict__ W1f,
    float* __restrict__ agg)
{
  __shared__ float h1s[4][16][33];   // [wave][e][k], k=32 is ones-row
  __shared__ f16 neighs[4][16][40];  // padded rows (80 B: 16B-aligned, 2-way banks = free)
  int t = threadIdx.x;
  int wave = t >> 6, l = t & 63;
  int e0 = (blockIdx.x * 4 + wave) * 16;
  const int* colp = ei + E_EDGES;

  // gather neigh = x[col[e]] -> f16 LDS
  {
    int eL = l >> 2, j0 = (l & 3) * 8;
    int c = colp[e0 + eL];
    const float* xr = x + (long)c * HID + j0;
    float4 v0 = *(const float4*)(xr);
    float4 v1 = *(const float4*)(xr + 4);
    f16* dst = &neighs[wave][eL][j0];
    dst[0]=(f16)v0.x; dst[1]=(f16)v0.y; dst[2]=(f16)v0.z; dst[3]=(f16)v0.w;
    dst[4]=(f16)v1.x; dst[5]=(f16)v1.y; dst[6]=(f16)v1.z; dst[7]=(f16)v1.w;
  }

  int m16 = l & 15, g4 = l >> 4;

  // GEMM1: h1[16e x 32k] = relu(EA[16e x 128d] @ W1[128d x 32k] + b1)
  f32x4 acc0 = {0.f,0.f,0.f,0.f}, acc1 = {0.f,0.f,0.f,0.f};
  const float* ea_base = ea + (long)(e0 + m16) * EDIM + g4 * 8;
  #pragma unroll
  for (int c = 0; c < 4; ++c) {
    float4 u0 = *(const float4*)(ea_base + c * 32);
    float4 u1 = *(const float4*)(ea_base + c * 32 + 4);
    f16x8 a;
    a[0]=(f16)u0.x; a[1]=(f16)u0.y; a[2]=(f16)u0.z; a[3]=(f16)u0.w;
    a[4]=(f16)u1.x; a[5]=(f16)u1.y; a[6]=(f16)u1.z; a[7]=(f16)u1.w;
    f16x8 b0  = *(const f16x8*)(W1f + ((c * 2 + 0) * 64 + l) * 8);
    f16x8 b1v = *(const f16x8*)(W1f + ((c * 2 + 1) * 64 + l) * 8);
    acc0 = __builtin_amdgcn_mfma_f32_16x16x32_f16(a, b0,  acc0, 0, 0, 0);
    acc1 = __builtin_amdgcn_mfma_f32_16x16x32_f16(a, b1v, acc1, 0, 0, 0);
  }
  // C/D: row e = (l>>4)*4 + r, col k = m16 (+16)
  float bb0 = b1[m16], bb1 = b1[m16 + 16];
  #pragma unroll
  for (int r = 0; r < 4; ++r) {
    h1s[wave][g4 * 4 + r][m16]      = fmaxf(acc0[r] + bb0, 0.f);
    h1s[wave][g4 * 4 + r][m16 + 16] = fmaxf(acc1[r] + bb1, 0.f);
  }
  if (m16 == 0) {
    #pragma unroll
    for (int r = 0; r < 4; ++r) h1s[wave][g4 * 4 + r][32] = 1.f;
  }
  __syncthreads();

  // GEMM2: messages[16e x 32i] = Z[16e x 33*32] @ W; chunk c2 has k=c2, j=(l>>4)*8+r
  f32x4 mc0 = {0.f,0.f,0.f,0.f}, mc1 = {0.f,0.f,0.f,0.f};
  f16x8 nv = *(const f16x8*)&neighs[wave][m16][g4 * 8];  // loop-invariant
  for (int c2 = 0; c2 < 33; ++c2) {
    f16 hv = (f16)h1s[wave][m16][c2];
    f16x8 hs8 = {hv,hv,hv,hv,hv,hv,hv,hv};
    f16x8 a = nv * hs8;
    f16x8 b0  = *(const f16x8*)(Wf + ((c2 * 2 + 0) * 64 + l) * 8);
    f16x8 b1v = *(const f16x8*)(Wf + ((c2 * 2 + 1) * 64 + l) * 8);
    mc0 = __builtin_amdgcn_mfma_f32_16x16x32_f16(a, b0,  mc0, 0, 0, 0);
    mc1 = __builtin_amdgcn_mfma_f32_16x16x32_f16(a, b1v, mc1, 0, 0, 0);
  }

  // scatter-add into agg[row[e]]
  const int* rowp = ei;
  #pragma unroll
  for (int r = 0; r < 4; ++r) {
    int er = rowp[e0 + g4 * 4 + r];
    atomicAdd(&agg[er * HID + m16],      mc0[r]);
    atomicAdd(&agg[er * HID + m16 + 16], mc1[r]);
  }
}

// ---------------- MX = agg @ gru_kernel + b_in  [NN x 96] ----------------
__global__ __launch_bounds__(256) void mx_kernel(
    const float* __restrict__ agg, const float* __restrict__ gk,
    const float* __restrict__ gb, float* __restrict__ MX)
{
  int tid = blockIdx.x * 256 + threadIdx.x;
  if (tid >= NN * 96) return;
  int n = tid / 96, c = tid - n * 96;
  float s = gb[c];  // b_in
  const float* ar = agg + n * HID;
  #pragma unroll
  for (int j = 0; j < 32; ++j) s = fmaf(ar[j], gk[j * 96 + c], s);
  MX[tid] = s;
}

// ---------------- sequential GRU scan: 1 wave ----------------
// lanes 0-31: z-gate col o + h state; lanes 32-63: r-gate col o. All lanes: full rh dot.
__global__ __launch_bounds__(64) void gru_scan(
    const float* __restrict__ MX, const float* __restrict__ grk,
    const float* __restrict__ gb, const float* __restrict__ hs,
    float* __restrict__ out)
{
  int l = threadIdx.x;
  int o = l & 31, g = l >> 5;
  float rg[32], rhc[32];
  #pragma unroll
  for (int j = 0; j < 32; ++j) rg[j]  = grk[j * 96 + g * 32 + o];
  #pragma unroll
  for (int j = 0; j < 32; ++j) rhc[j] = grk[j * 96 + 64 + o];
  float bg  = gb[96 + g * 32 + o];   // b_rec gate part
  float brh = gb[96 + 64 + o];       // b_rec h part
  float hcur = hs[o];
  float mxg = MX[g * 32 + o];
  float mxh = MX[64 + o];

  for (int ts = 0; ts < NN; ++ts) {
    int tn = (ts + 1 < NN) ? ts + 1 : ts;
    float nmxg = MX[tn * 96 + g * 32 + o];   // prefetch next step
    float nmxh = MX[tn * 96 + 64 + o];

    float sh[32];
    #pragma unroll
    for (int j = 0; j < 32; ++j)
      sh[j] = __int_as_float(__builtin_amdgcn_readlane(__float_as_int(hcur), j));

    float a0=0.f,a1=0.f,a2=0.f,a3=0.f,p0=0.f,p1=0.f,p2=0.f,p3=0.f;
    #pragma unroll
    for (int j = 0; j < 32; j += 4) {
      a0 = fmaf(sh[j],   rg[j],   a0);
      a1 = fmaf(sh[j+1], rg[j+1], a1);
      a2 = fmaf(sh[j+2], rg[j+2], a2);
      a3 = fmaf(sh[j+3], rg[j+3], a3);
      p0 = fmaf(sh[j],   rhc[j],   p0);
      p1 = fmaf(sh[j+1], rhc[j+1], p1);
      p2 = fmaf(sh[j+2], rhc[j+2], p2);
      p3 = fmaf(sh[j+3], rhc[j+3], p3);
    }
    float mg  = ((a0 + a1) + (a2 + a3)) + bg;
    float rhv = ((p0 + p1) + (p2 + p3)) + brh;
    // gate: lanes<32 -> z, lanes>=32 -> r
    float gate = __builtin_amdgcn_rcpf(1.f + __builtin_amdgcn_exp2f(-1.442695041f * (mxg + mg)));
    float rr = __shfl_xor(gate, 32);     // lanes<32 receive r
    if (l < 32) {
      float pre = mxh + rr * rhv;
      float av = fabsf(pre);
      float e2 = __builtin_amdgcn_exp2f(av * 2.885390082f);  // e^(2|x|)
      float th = 1.f - 2.f * __builtin_amdgcn_rcpf(e2 + 1.f);
      th = copysignf(th, pre);
      float hn = gate * hcur + (1.f - gate) * th;
      out[ts * HID + o] = hn;
      hcur = hn;
    }
    mxg = nmxg; mxh = nmxh;
  }
  if (l < 32) out[NN * HID + o] = hcur;
}

extern "C" void kernel_launch(void* const* d_in, const int* in_sizes, int n_in,
                              void* d_out, int out_size, void* d_ws, size_t ws_size,
                              hipStream_t stream) {
  const float* x   = (const float*)d_in[0];
  const int*   ei  = (const int*)d_in[1];
  const float* ea  = (const float*)d_in[2];
  const float* hs  = (const float*)d_in[3];
  const float* w1  = (const float*)d_in[4];
  const float* b1  = (const float*)d_in[5];
  const float* w2  = (const float*)d_in[6];
  const float* b2  = (const float*)d_in[7];
  const float* gk  = (const float*)d_in[8];
  const float* grk = (const float*)d_in[9];
  const float* gb  = (const float*)d_in[10];
  float* out = (float*)d_out;

  char* ws = (char*)d_ws;
  float* agg = (float*)ws;                                   // 320000 f32
  float* MX  = (float*)(ws + (size_t)320000 * 4);            // 960000 f32
  f16*   Wf  = (f16*)(ws + (size_t)(320000 + 960000) * 4);   // 33792 f16
  f16*   W1f = Wf + 33 * 1024;                               // 4096 f16

  prep_kernel<<<dim3(1250), dim3(256), 0, stream>>>(w1, w2, b2, agg, Wf, W1f);
  edges_kernel<<<dim3(E_EDGES / 64), dim3(256), 0, stream>>>(x, ei, ea, b1, Wf, W1f, agg);
  mx_kernel<<<dim3((NN * 96 + 255) / 256), dim3(256), 0, stream>>>(agg, gk, gb, MX);
  gru_scan<<<dim3(1), dim3(64), 0, stream>>>(MX, grk, gb, hs, out);
}

// Round 3
// 2454.884 us; speedup vs baseline: 1.5344x; 1.5344x over previous
//
#include <hip/hip_runtime.h>

#define E_EDGES 640000
#define NN 10000
#define HID 32
#define EDIM 128
#define CH 50     // GRU steps per LDS chunk
#define NCH 200   // NN / CH

typedef _Float16 f16;
typedef _Float16 f16x8 __attribute__((ext_vector_type(8)));
typedef _Float16 f16x2 __attribute__((ext_vector_type(2)));
typedef float f32x4 __attribute__((ext_vector_type(4)));

static __device__ __forceinline__ f16x2 pkrtz(float a, float b) {
  auto t = __builtin_amdgcn_cvt_pkrtz(a, b);   // __fp16 ext_vector(2)
  f16x2 r;
  __builtin_memcpy(&r, &t, 4);
  return r;
}

// ---------------- prep: zero agg, build f16 fragment-ordered weights ----------------
__global__ __launch_bounds__(256) void prep_kernel(
    const float* __restrict__ w1, const float* __restrict__ w2,
    const float* __restrict__ b2, float* __restrict__ agg,
    f16* __restrict__ Wf, f16* __restrict__ W1f)
{
  int tid = blockIdx.x * 256 + threadIdx.x;
  if (tid < NN * HID) agg[tid] = 0.f;
  if (tid < 33 * 1024) {
    int r = tid & 7, l = (tid >> 3) & 63, h = (tid >> 9) & 1, c2 = tid >> 10;
    int i = (l & 15) + 16 * h, j = (l >> 4) * 8 + r;
    float v = (c2 < 32) ? w2[c2 * 1024 + i * 32 + j] : b2[i * 32 + j];
    Wf[tid] = (f16)v;
  }
  if (tid < 4 * 1024) {
    int r = tid & 7, l = (tid >> 3) & 63, h = (tid >> 9) & 1, c = tid >> 10;
    int d = c * 32 + (l >> 4) * 8 + r, k = (l & 15) + 16 * h;
    W1f[tid] = (f16)w1[d * 32 + k];
  }
}

// ---------------- edges: h1 = relu(ea@W1+b1); messages = Z@W; atomic scatter ----------------
__global__ __launch_bounds__(256) void edges_kernel(
    const float* __restrict__ x, const int* __restrict__ ei,
    const float* __restrict__ ea, const float* __restrict__ b1,
    const f16* __restrict__ Wf, const f16* __restrict__ W1f,
    float* __restrict__ agg)
{
  __shared__ float h1s[4][16][33];
  __shared__ f16 neighs[4][16][40];
  int t = threadIdx.x;
  int wave = t >> 6, l = t & 63;
  int e0 = (blockIdx.x * 4 + wave) * 16;
  const int* colp = ei + E_EDGES;

  {
    int eL = l >> 2, j0 = (l & 3) * 8;
    int c = colp[e0 + eL];
    const float* xr = x + (long)c * HID + j0;
    float4 v0 = *(const float4*)(xr);
    float4 v1 = *(const float4*)(xr + 4);
    f16* dst = &neighs[wave][eL][j0];
    dst[0]=(f16)v0.x; dst[1]=(f16)v0.y; dst[2]=(f16)v0.z; dst[3]=(f16)v0.w;
    dst[4]=(f16)v1.x; dst[5]=(f16)v1.y; dst[6]=(f16)v1.z; dst[7]=(f16)v1.w;
  }

  int m16 = l & 15, g4 = l >> 4;

  f32x4 acc0 = {0.f,0.f,0.f,0.f}, acc1 = {0.f,0.f,0.f,0.f};
  const float* ea_base = ea + (long)(e0 + m16) * EDIM + g4 * 8;
  #pragma unroll
  for (int c = 0; c < 4; ++c) {
    float4 u0 = *(const float4*)(ea_base + c * 32);
    float4 u1 = *(const float4*)(ea_base + c * 32 + 4);
    f16x8 a;
    a[0]=(f16)u0.x; a[1]=(f16)u0.y; a[2]=(f16)u0.z; a[3]=(f16)u0.w;
    a[4]=(f16)u1.x; a[5]=(f16)u1.y; a[6]=(f16)u1.z; a[7]=(f16)u1.w;
    f16x8 b0  = *(const f16x8*)(W1f + ((c * 2 + 0) * 64 + l) * 8);
    f16x8 b1v = *(const f16x8*)(W1f + ((c * 2 + 1) * 64 + l) * 8);
    acc0 = __builtin_amdgcn_mfma_f32_16x16x32_f16(a, b0,  acc0, 0, 0, 0);
    acc1 = __builtin_amdgcn_mfma_f32_16x16x32_f16(a, b1v, acc1, 0, 0, 0);
  }
  float bb0 = b1[m16], bb1 = b1[m16 + 16];
  #pragma unroll
  for (int r = 0; r < 4; ++r) {
    h1s[wave][g4 * 4 + r][m16]      = fmaxf(acc0[r] + bb0, 0.f);
    h1s[wave][g4 * 4 + r][m16 + 16] = fmaxf(acc1[r] + bb1, 0.f);
  }
  if (m16 == 0) {
    #pragma unroll
    for (int r = 0; r < 4; ++r) h1s[wave][g4 * 4 + r][32] = 1.f;
  }
  __syncthreads();

  f32x4 mc0 = {0.f,0.f,0.f,0.f}, mc1 = {0.f,0.f,0.f,0.f};
  f16x8 nv = *(const f16x8*)&neighs[wave][m16][g4 * 8];
  for (int c2 = 0; c2 < 33; ++c2) {
    f16 hv = (f16)h1s[wave][m16][c2];
    f16x8 hs8 = {hv,hv,hv,hv,hv,hv,hv,hv};
    f16x8 a = nv * hs8;
    f16x8 b0  = *(const f16x8*)(Wf + ((c2 * 2 + 0) * 64 + l) * 8);
    f16x8 b1v = *(const f16x8*)(Wf + ((c2 * 2 + 1) * 64 + l) * 8);
    mc0 = __builtin_amdgcn_mfma_f32_16x16x32_f16(a, b0,  mc0, 0, 0, 0);
    mc1 = __builtin_amdgcn_mfma_f32_16x16x32_f16(a, b1v, mc1, 0, 0, 0);
  }

  const int* rowp = ei;
  #pragma unroll
  for (int r = 0; r < 4; ++r) {
    int er = rowp[e0 + g4 * 4 + r];
    atomicAdd(&agg[er * HID + m16],      mc0[r]);
    atomicAdd(&agg[er * HID + m16 + 16], mc1[r]);
  }
}

// ---------------- MXp[n][lane][2]: lane-arranged input-side GRU matvec ----------------
// p=0 -> col l (z cols for l<32, r cols for l>=32), p=1 -> col 64+(l&31) (h part)
__global__ __launch_bounds__(256) void mxp_kernel(
    const float* __restrict__ agg, const float* __restrict__ gk,
    const float* __restrict__ gb, float* __restrict__ MXp)
{
  int tid = blockIdx.x * 256 + threadIdx.x;
  if (tid >= NN * 128) return;
  int n = tid >> 7, r = tid & 127, l = r >> 1, p = r & 1;
  int c = p ? (64 + (l & 31)) : l;
  float s = gb[c];
  const float* ar = agg + n * HID;
  #pragma unroll
  for (int j = 0; j < 32; ++j) s = fmaf(ar[j], gk[j * 96 + c], s);
  MXp[tid] = s;
}

// ---------------- sequential GRU scan: 1 wave, LDS-staged MXp, f16-pair dots ----------------
__global__ __launch_bounds__(64) void gru_scan(
    const float* __restrict__ MXp, const float* __restrict__ grk,
    const float* __restrict__ gb, const float* __restrict__ hs,
    float* __restrict__ out)
{
  __shared__ float lds[2 * CH * 128];   // 51.2 KB: two chunks of CH steps x 512B
  int l = threadIdx.x;
  int o = l & 31;

  // recurrent weights packed as f16 pairs; gate col = l (z for l<32, r for l>=32)
  f16x2 rgp[16], rhp[16];
  #pragma unroll
  for (int j = 0; j < 16; ++j) {
    rgp[j] = pkrtz(grk[(2*j)*96 + l],      grk[(2*j+1)*96 + l]);
    rhp[j] = pkrtz(grk[(2*j)*96 + 64 + o], grk[(2*j+1)*96 + 64 + o]);
  }
  float bg  = gb[96 + l];
  float brh = gb[96 + 64 + o];
  float hcur = hs[o];

  const char* src = (const char*)MXp;
  // stage chunk 0
  #pragma unroll
  for (int i = 0; i < 25; ++i)
    __builtin_amdgcn_global_load_lds(
        (const __attribute__((address_space(1))) void*)(src + i * 1024 + l * 16),
        (__attribute__((address_space(3))) void*)((char*)lds + i * 1024), 16, 0, 0);

  float* outp = out + o;

  for (int ck = 0; ck < NCH; ++ck) {
    asm volatile("s_waitcnt vmcnt(0)" ::: "memory");  // current chunk ready; stores drained
    if (ck + 1 < NCH) {
      const char* s2 = src + (size_t)(ck + 1) * CH * 512;
      char* dbuf = (char*)lds + ((ck + 1) & 1) * CH * 512;
      #pragma unroll
      for (int i = 0; i < 25; ++i)
        __builtin_amdgcn_global_load_lds(
            (const __attribute__((address_space(1))) void*)(s2 + i * 1024 + l * 16),
            (__attribute__((address_space(3))) void*)(dbuf + i * 1024), 16, 0, 0);
    }
    const float* buf = lds + (ck & 1) * CH * 128;

    #pragma unroll 2
    for (int s = 0; s < CH; ++s) {
      float2 mx2 = *(const float2*)(buf + s * 128 + l * 2);

      // pack (h[2j], h[2j+1]) into odd lanes via DPP quad_perm(1,0,3,2) + cvt_pkrtz
      int hb = __float_as_int(hcur);
      int nb = __builtin_amdgcn_update_dpp(hb, hb, 0xB1, 0xF, 0xF, true);
      f16x2 pk = pkrtz(__int_as_float(nb), hcur);
      int pki;
      __builtin_memcpy(&pki, &pk, 4);

      float a0=0.f,a1=0.f,a2=0.f,a3=0.f,p0=0.f,p1=0.f,p2=0.f,p3=0.f;
      #pragma unroll
      for (int j = 0; j < 16; ++j) {
        int shi = __builtin_amdgcn_readlane(pki, 2 * j + 1);
        f16x2 shp;
        __builtin_memcpy(&shp, &shi, 4);
#if __has_builtin(__builtin_amdgcn_fdot2)
        float* ag = (j & 2) ? ((j & 1) ? &a3 : &a2) : ((j & 1) ? &a1 : &a0);
        float* pg = (j & 2) ? ((j & 1) ? &p3 : &p2) : ((j & 1) ? &p1 : &p0);
        *ag = __builtin_amdgcn_fdot2(shp, rgp[j], *ag, false);
        *pg = __builtin_amdgcn_fdot2(shp, rhp[j], *pg, false);
#else
        float s0 = (float)shp[0], s1 = (float)shp[1];
        a0 = fmaf(s0, (float)rgp[j][0], a0); a1 = fmaf(s1, (float)rgp[j][1], a1);
        p0 = fmaf(s0, (float)rhp[j][0], p0); p1 = fmaf(s1, (float)rhp[j][1], p1);
#endif
      }
      float mg  = ((a0 + a1) + (a2 + a3)) + bg;
      float rhv = ((p0 + p1) + (p2 + p3)) + brh;

      float t = mx2.x + mg;
      float gate = __builtin_amdgcn_rcpf(1.f + __builtin_amdgcn_exp2f(-1.442695041f * t));
      float oth = __shfl_xor(gate, 32);
      float zv = (l < 32) ? gate : oth;
      float rv = (l < 32) ? oth  : gate;

      float pre = mx2.y + rv * rhv;
      float av = fabsf(pre);
      float e2 = __builtin_amdgcn_exp2f(av * 2.885390082f);
      float th = 1.f - 2.f * __builtin_amdgcn_rcpf(e2 + 1.f);
      th = copysignf(th, pre);

      float hn = fmaf(zv, hcur - th, th);
      if (l < 32) outp[s * HID] = hn;
      hcur = hn;
    }
    outp += CH * HID;
  }
  if (l < 32) out[NN * HID + o] = hcur;
}

extern "C" void kernel_launch(void* const* d_in, const int* in_sizes, int n_in,
                              void* d_out, int out_size, void* d_ws, size_t ws_size,
                              hipStream_t stream) {
  const float* x   = (const float*)d_in[0];
  const int*   ei  = (const int*)d_in[1];
  const float* ea  = (const float*)d_in[2];
  const float* hs  = (const float*)d_in[3];
  const float* w1  = (const float*)d_in[4];
  const float* b1  = (const float*)d_in[5];
  const float* w2  = (const float*)d_in[6];
  const float* b2  = (const float*)d_in[7];
  const float* gk  = (const float*)d_in[8];
  const float* grk = (const float*)d_in[9];
  const float* gb  = (const float*)d_in[10];
  float* out = (float*)d_out;

  char* ws = (char*)d_ws;
  float* agg = (float*)ws;                                     // 320000 f32
  float* MXp = (float*)(ws + (size_t)320000 * 4);              // 1,280,000 f32
  f16*   Wf  = (f16*)(ws + (size_t)(320000 + 1280000) * 4);    // 33792 f16
  f16*   W1f = Wf + 33 * 1024;                                 // 4096 f16

  prep_kernel<<<dim3(1250), dim3(256), 0, stream>>>(w1, w2, b2, agg, Wf, W1f);
  edges_kernel<<<dim3(E_EDGES / 64), dim3(256), 0, stream>>>(x, ei, ea, b1, Wf, W1f, agg);
  mxp_kernel<<<dim3((NN * 128 + 255) / 256), dim3(256), 0, stream>>>(agg, gk, gb, MXp);
  gru_scan<<<dim3(1), dim3(64), 0, stream>>>(MXp, grk, gb, hs, out);
}

// Round 4
// 2274.755 us; speedup vs baseline: 1.6559x; 1.0792x over previous
//
#include <hip/hip_runtime.h>

#define E_EDGES 640000
#define NN 10000
#define HID 32
#define EDIM 128
#define CH 50     // GRU steps per LDS chunk
#define NCH 200   // NN / CH

typedef _Float16 f16;
typedef _Float16 f16x8 __attribute__((ext_vector_type(8)));
typedef _Float16 f16x2 __attribute__((ext_vector_type(2)));
typedef float f32x4 __attribute__((ext_vector_type(4)));

static __device__ __forceinline__ f16x2 pkrtz(float a, float b) {
  auto t = __builtin_amdgcn_cvt_pkrtz(a, b);   // __fp16 ext_vector(2)
  f16x2 r;
  __builtin_memcpy(&r, &t, 4);
  return r;
}

// ---------------- prep: zero agg, build f16 fragment-ordered weights ----------------
__global__ __launch_bounds__(256) void prep_kernel(
    const float* __restrict__ w1, const float* __restrict__ w2,
    const float* __restrict__ b2, float* __restrict__ agg,
    f16* __restrict__ Wf, f16* __restrict__ W1f)
{
  int tid = blockIdx.x * 256 + threadIdx.x;
  if (tid < NN * HID) agg[tid] = 0.f;
  if (tid < 33 * 1024) {
    int r = tid & 7, l = (tid >> 3) & 63, h = (tid >> 9) & 1, c2 = tid >> 10;
    int i = (l & 15) + 16 * h, j = (l >> 4) * 8 + r;
    float v = (c2 < 32) ? w2[c2 * 1024 + i * 32 + j] : b2[i * 32 + j];
    Wf[tid] = (f16)v;
  }
  if (tid < 4 * 1024) {
    int r = tid & 7, l = (tid >> 3) & 63, h = (tid >> 9) & 1, c = tid >> 10;
    int d = c * 32 + (l >> 4) * 8 + r, k = (l & 15) + 16 * h;
    W1f[tid] = (f16)w1[d * 32 + k];
  }
}

// ---------------- edges: h1 = relu(ea@W1+b1); messages = Z@W; atomic scatter ----------------
__global__ __launch_bounds__(256) void edges_kernel(
    const float* __restrict__ x, const int* __restrict__ ei,
    const float* __restrict__ ea, const float* __restrict__ b1,
    const f16* __restrict__ Wf, const f16* __restrict__ W1f,
    float* __restrict__ agg)
{
  __shared__ float h1s[4][16][33];
  __shared__ f16 neighs[4][16][40];
  int t = threadIdx.x;
  int wave = t >> 6, l = t & 63;
  int e0 = (blockIdx.x * 4 + wave) * 16;
  const int* colp = ei + E_EDGES;

  {
    int eL = l >> 2, j0 = (l & 3) * 8;
    int c = colp[e0 + eL];
    const float* xr = x + (long)c * HID + j0;
    float4 v0 = *(const float4*)(xr);
    float4 v1 = *(const float4*)(xr + 4);
    f16* dst = &neighs[wave][eL][j0];
    dst[0]=(f16)v0.x; dst[1]=(f16)v0.y; dst[2]=(f16)v0.z; dst[3]=(f16)v0.w;
    dst[4]=(f16)v1.x; dst[5]=(f16)v1.y; dst[6]=(f16)v1.z; dst[7]=(f16)v1.w;
  }

  int m16 = l & 15, g4 = l >> 4;

  f32x4 acc0 = {0.f,0.f,0.f,0.f}, acc1 = {0.f,0.f,0.f,0.f};
  const float* ea_base = ea + (long)(e0 + m16) * EDIM + g4 * 8;
  #pragma unroll
  for (int c = 0; c < 4; ++c) {
    float4 u0 = *(const float4*)(ea_base + c * 32);
    float4 u1 = *(const float4*)(ea_base + c * 32 + 4);
    f16x8 a;
    a[0]=(f16)u0.x; a[1]=(f16)u0.y; a[2]=(f16)u0.z; a[3]=(f16)u0.w;
    a[4]=(f16)u1.x; a[5]=(f16)u1.y; a[6]=(f16)u1.z; a[7]=(f16)u1.w;
    f16x8 b0  = *(const f16x8*)(W1f + ((c * 2 + 0) * 64 + l) * 8);
    f16x8 b1v = *(const f16x8*)(W1f + ((c * 2 + 1) * 64 + l) * 8);
    acc0 = __builtin_amdgcn_mfma_f32_16x16x32_f16(a, b0,  acc0, 0, 0, 0);
    acc1 = __builtin_amdgcn_mfma_f32_16x16x32_f16(a, b1v, acc1, 0, 0, 0);
  }
  float bb0 = b1[m16], bb1 = b1[m16 + 16];
  #pragma unroll
  for (int r = 0; r < 4; ++r) {
    h1s[wave][g4 * 4 + r][m16]      = fmaxf(acc0[r] + bb0, 0.f);
    h1s[wave][g4 * 4 + r][m16 + 16] = fmaxf(acc1[r] + bb1, 0.f);
  }
  if (m16 == 0) {
    #pragma unroll
    for (int r = 0; r < 4; ++r) h1s[wave][g4 * 4 + r][32] = 1.f;
  }
  __syncthreads();

  f32x4 mc0 = {0.f,0.f,0.f,0.f}, mc1 = {0.f,0.f,0.f,0.f};
  f16x8 nv = *(const f16x8*)&neighs[wave][m16][g4 * 8];
  for (int c2 = 0; c2 < 33; ++c2) {
    f16 hv = (f16)h1s[wave][m16][c2];
    f16x8 hs8 = {hv,hv,hv,hv,hv,hv,hv,hv};
    f16x8 a = nv * hs8;
    f16x8 b0  = *(const f16x8*)(Wf + ((c2 * 2 + 0) * 64 + l) * 8);
    f16x8 b1v = *(const f16x8*)(Wf + ((c2 * 2 + 1) * 64 + l) * 8);
    mc0 = __builtin_amdgcn_mfma_f32_16x16x32_f16(a, b0,  mc0, 0, 0, 0);
    mc1 = __builtin_amdgcn_mfma_f32_16x16x32_f16(a, b1v, mc1, 0, 0, 0);
  }

  const int* rowp = ei;
  #pragma unroll
  for (int r = 0; r < 4; ++r) {
    int er = rowp[e0 + g4 * 4 + r];
    atomicAdd(&agg[er * HID + m16],      mc0[r]);
    atomicAdd(&agg[er * HID + m16 + 16], mc1[r]);
  }
}

// ---------------- MXp[n][lane][2]: lane-arranged input-side GRU matvec ----------------
__global__ __launch_bounds__(256) void mxp_kernel(
    const float* __restrict__ agg, const float* __restrict__ gk,
    const float* __restrict__ gb, float* __restrict__ MXp)
{
  int tid = blockIdx.x * 256 + threadIdx.x;
  if (tid >= NN * 128) return;
  int n = tid >> 7, r = tid & 127, l = r >> 1, p = r & 1;
  int c = p ? (64 + (l & 31)) : l;
  float s = gb[c];
  const float* ar = agg + n * HID;
  #pragma unroll
  for (int j = 0; j < 32; ++j) s = fmaf(ar[j], gk[j * 96 + c], s);
  MXp[tid] = s;
}

// ---------------- sequential GRU scan: 1 wave ----------------
__global__ __launch_bounds__(64) void gru_scan(
    const float* __restrict__ MXp, const float* __restrict__ grk,
    const float* __restrict__ gb, const float* __restrict__ hs,
    float* __restrict__ out)
{
  __shared__ float lds[2 * CH * 128 + 128];   // +128: dead last-prefetch stays in-bounds
  int l = threadIdx.x;
  int o = l & 31;
  bool low = (l < 32);

  // recurrent weights as f16 pairs; gate col = l (z for l<32, r for l>=32)
  f16x2 rgp[16], rhp[16];
  #pragma unroll
  for (int j = 0; j < 16; ++j) {
    rgp[j] = pkrtz(grk[(2*j)*96 + l],      grk[(2*j+1)*96 + l]);
    rhp[j] = pkrtz(grk[(2*j)*96 + 64 + o], grk[(2*j+1)*96 + 64 + o]);
  }
  float bg  = gb[96 + l];
  float brh = gb[96 + 64 + o];
  float hcur = hs[o];

  const char* src = (const char*)MXp;
  // stage chunk 0
  #pragma unroll
  for (int i = 0; i < 25; ++i)
    __builtin_amdgcn_global_load_lds(
        (const __attribute__((address_space(1))) void*)(src + i * 1024 + l * 16),
        (__attribute__((address_space(3))) void*)((char*)lds + i * 1024), 16, 0, 0);

  float* outp = out + o;

  for (int ck = 0; ck < NCH; ++ck) {
    asm volatile("s_waitcnt vmcnt(0)" ::: "memory");  // chunk ck DMA landed; stores drained
    if (ck + 1 < NCH) {
      const char* s2 = src + (size_t)(ck + 1) * CH * 512;
      char* dbuf = (char*)lds + ((ck + 1) & 1) * CH * 512;
      #pragma unroll
      for (int i = 0; i < 25; ++i)
        __builtin_amdgcn_global_load_lds(
            (const __attribute__((address_space(1))) void*)(s2 + i * 1024 + l * 16),
            (__attribute__((address_space(3))) void*)(dbuf + i * 1024), 16, 0, 0);
    }
    const float* buf = lds + (ck & 1) * CH * 128;
    float2 mx_cur = *(const float2*)(buf + l * 2);   // one exposed ds_read per chunk

    #pragma unroll 2
    for (int s = 0; s < CH; ++s) {
      // prefetch next step's mx (dead at s=CH-1, in-bounds via pad)
      float2 mx_nxt = *(const float2*)(buf + (s + 1) * 128 + l * 2);

      // pack (h[2j], h[2j+1]) into odd lanes via DPP quad_perm(1,0,3,2) + cvt_pkrtz
      int hb = __float_as_int(hcur);
      int nb = __builtin_amdgcn_update_dpp(hb, hb, 0xB1, 0xF, 0xF, true);
      f16x2 pk = pkrtz(__int_as_float(nb), hcur);
      int pki;
      __builtin_memcpy(&pki, &pk, 4);

      // gate dot (z in low half, r in high half) + full rh dot, biases/mx folded into init
      float a0 = bg, a1 = mx_cur.x, a2 = 0.f, a3 = 0.f;
      float p0 = brh, p1 = 0.f, p2 = 0.f, p3 = 0.f;
      #pragma unroll
      for (int j = 0; j < 16; ++j) {
        int shi = __builtin_amdgcn_readlane(pki, 2 * j + 1);
        f16x2 shp;
        __builtin_memcpy(&shp, &shi, 4);
        float* ag = (j & 2) ? ((j & 1) ? &a3 : &a2) : ((j & 1) ? &a1 : &a0);
        float* pg = (j & 2) ? ((j & 1) ? &p3 : &p2) : ((j & 1) ? &p1 : &p0);
        *ag = __builtin_amdgcn_fdot2(shp, rgp[j], *ag, false);
        *pg = __builtin_amdgcn_fdot2(shp, rhp[j], *pg, false);
      }
      float t   = (a0 + a1) + (a2 + a3);
      float rhv = (p0 + p1) + (p2 + p3);

      float gate = __builtin_amdgcn_rcpf(1.f + __builtin_amdgcn_exp2f(-1.442695041f * t));

      // exchange z<->r across wave halves (VALU permlane, orientation-free)
      float other;
#if __has_builtin(__builtin_amdgcn_permlane32_swap)
      {
        int gi = __float_as_int(gate);
        auto sw = __builtin_amdgcn_permlane32_swap(gi, gi, false, false);
        int pr[2];
        __builtin_memcpy(pr, &sw, 8);
        other = (__int_as_float(pr[0]) + __int_as_float(pr[1])) - gate;
      }
#else
      other = __shfl_xor(gate, 32);
#endif
      float zv = low ? gate : other;
      float rv = low ? other : gate;

      float pre = fmaf(rv, rhv, mx_cur.y);
      float e2 = __builtin_amdgcn_exp2f(fabsf(pre) * 2.885390082f);
      float rc = __builtin_amdgcn_rcpf(e2 + 1.f);
      float th = fmaf(-2.f, rc, 1.f);
      th = copysignf(th, pre);

      float hn = fmaf(zv, hcur - th, th);
      outp[s * HID] = hn;            // all 64 lanes: dup-write identical value
      hcur = hn;
      mx_cur = mx_nxt;
    }
    outp += CH * HID;
  }
  out[NN * HID + o] = hcur;
}

extern "C" void kernel_launch(void* const* d_in, const int* in_sizes, int n_in,
                              void* d_out, int out_size, void* d_ws, size_t ws_size,
                              hipStream_t stream) {
  const float* x   = (const float*)d_in[0];
  const int*   ei  = (const int*)d_in[1];
  const float* ea  = (const float*)d_in[2];
  const float* hs  = (const float*)d_in[3];
  const float* w1  = (const float*)d_in[4];
  const float* b1  = (const float*)d_in[5];
  const float* w2  = (const float*)d_in[6];
  const float* b2  = (const float*)d_in[7];
  const float* gk  = (const float*)d_in[8];
  const float* grk = (const float*)d_in[9];
  const float* gb  = (const float*)d_in[10];
  float* out = (float*)d_out;

  char* ws = (char*)d_ws;
  float* agg = (float*)ws;                                     // 320000 f32
  float* MXp = (float*)(ws + (size_t)320000 * 4);              // 1,280,000 f32
  f16*   Wf  = (f16*)(ws + (size_t)(320000 + 1280000) * 4);    // 33792 f16
  f16*   W1f = Wf + 33 * 1024;                                 // 4096 f16

  prep_kernel<<<dim3(1250), dim3(256), 0, stream>>>(w1, w2, b2, agg, Wf, W1f);
  edges_kernel<<<dim3(E_EDGES / 64), dim3(256), 0, stream>>>(x, ei, ea, b1, Wf, W1f, agg);
  mxp_kernel<<<dim3((NN * 128 + 255) / 256), dim3(256), 0, stream>>>(agg, gk, gb, MXp);
  gru_scan<<<dim3(1), dim3(64), 0, stream>>>(MXp, grk, gb, hs, out);
}